// Round 1
// 1291.336 us; speedup vs baseline: 1.0124x; 1.0124x over previous
//
#include <hip/hip_runtime.h>
#include <math.h>

namespace {
constexpr int kN = 16384;
constexpr int kD = 2048;
constexpr int kH = 4096;
constexpr int kE = 64;
constexpr int kShared = 8;

// d_out layout (floats), reference return order
constexpr int OFF_GW = 0;                       // global_weights: N x 8
constexpr int OFF_LW = kN * kShared;            // local_weights:  N x 2
constexpr int OFF_LI = OFF_LW + kN * 2;         // local_indices:  N x 2 (as float)
constexpr int OFF_W  = OFF_LI + kN * 2;         // weights: N x 64 -- logit accumulator in atomic mode

constexpr int GS_STRIDE = 132;
constexpr int HSPLIT = 4;
constexpr int CHUNKS = 8;       // 8 x 128 = 1024 H-cols per block

// workspace layout (f16 elements from base)
constexpr size_t XH_OFF  = 0;
constexpr size_t XL_OFF  = (size_t)kN * kD;
constexpr size_t W1TH_OFF = XL_OFF + (size_t)kN * kD;
constexpr size_t W1TL_OFF = W1TH_OFF + (size_t)kH * kD;
constexpr size_t WS_BASE = (W1TL_OFF + (size_t)kH * kD) * 2;          // bytes: 167,772,160
constexpr size_t PART_FLOAT_OFF = WS_BASE / 4;                         // float index of partials
constexpr size_t WS_FULL = WS_BASE + (size_t)HSPLIT * kN * kE * 4;     // + 16.8 MB partials

// double-buffer geometry (f16 elements per buffer region)
constexpr int BUF_FLOATS = 64 * GS_STRIDE;      // 8448 floats = 33792 B per buffer
constexpr int BUF_F16    = BUF_FLOATS * 2;      // 16896 f16 slots (staging uses first 16384)
}

typedef _Float16 half8  __attribute__((ext_vector_type(8)));
typedef _Float16 half4t __attribute__((ext_vector_type(4)));
typedef float    f32x16 __attribute__((ext_vector_type(16)));

__device__ __forceinline__ void async16(const _Float16* g, _Float16* l) {
    __builtin_amdgcn_global_load_lds(
        (const __attribute__((address_space(1))) void*)g,
        (__attribute__((address_space(3))) void*)l, 16, 0, 0);
}

// ---------------------------------------------------------------------------
// Pre-pass 1: x (fp32) -> xh, xl (f16 planes; xl pre-scaled by 2048)
// ---------------------------------------------------------------------------
__global__ __launch_bounds__(256)
void convert_x(const float* __restrict__ x, _Float16* __restrict__ xh,
               _Float16* __restrict__ xl)
{
    const size_t i = ((size_t)blockIdx.x * 256 + threadIdx.x) * 4;
    const float4 v = *reinterpret_cast<const float4*>(x + i);
    half4t h, l;
    const float vs[4] = {v.x, v.y, v.z, v.w};
    #pragma unroll
    for (int j = 0; j < 4; ++j) {
        const _Float16 hj = (_Float16)vs[j];
        h[j] = hj;
        l[j] = (_Float16)((vs[j] - (float)hj) * 2048.0f);
    }
    *reinterpret_cast<half4t*>(xh + i) = h;
    *reinterpret_cast<half4t*>(xl + i) = l;
}

// ---------------------------------------------------------------------------
// Pre-pass 2: W1 [D][H] fp32 -> W1^T hi/lo planes [H][D] f16 (lo scaled 2048)
// ---------------------------------------------------------------------------
__global__ __launch_bounds__(256)
void convert_w1t(const float* __restrict__ W1, _Float16* __restrict__ th,
                 _Float16* __restrict__ tl)
{
    __shared__ float T[64][65];
    const int bk = blockIdx.x & 31;
    const int bn = blockIdx.x >> 5;
    const int k0 = bk * 64, n0 = bn * 64;
    const int t = threadIdx.x;
    const int c4 = (t & 15) * 4, r = t >> 4;

    #pragma unroll
    for (int i = 0; i < 4; ++i) {
        const int kk = r + 16 * i;
        const float4 v = *reinterpret_cast<const float4*>(
            W1 + (size_t)(k0 + kk) * kH + n0 + c4);
        T[kk][c4 + 0] = v.x; T[kk][c4 + 1] = v.y;
        T[kk][c4 + 2] = v.z; T[kk][c4 + 3] = v.w;
    }
    __syncthreads();
    #pragma unroll
    for (int i = 0; i < 4; ++i) {
        const int nn = r + 16 * i;
        half4t h, l;
        #pragma unroll
        for (int j = 0; j < 4; ++j) {
            const float vv = T[c4 + j][nn];
            const _Float16 hj = (_Float16)vv;
            h[j] = hj;
            l[j] = (_Float16)((vv - (float)hj) * 2048.0f);
        }
        *reinterpret_cast<half4t*>(th + (size_t)(n0 + nn) * kD + k0 + c4) = h;
        *reinterpret_cast<half4t*>(tl + (size_t)(n0 + nn) * kD + k0 + c4) = l;
    }
}

// ---------------------------------------------------------------------------
// GEMM1 split-f16 3-pass MFMA, fused gelu + GEMM2 partial.
// grid = 512 (hSplit = bx&3 -> per-XCD W1 locality), block = 256 (4 waves).
//
// R(this session): double-buffered LDS + counted-vmcnt 2-phase pipeline
// (T3/T4): issue next K-step's 8 global_load_lds BEFORE computing the
// current step, wait vmcnt(8) (next step's loads stay in flight across the
// barrier), raw s_barrier (no compiler vmcnt(0) drain). Prefetch chain is
// flattened across chunk boundaries; the chunk epilogue's gS aliases the
// just-read buffer while the prefetch sits in the other buffer.
// LDS staging keeps the source-permuted chunk swizzle:
// logical chunk q of row r lives at physical chunk q ^ (r&3) ^ ((r>>2)&3).
// ---------------------------------------------------------------------------
__global__ __launch_bounds__(256, 2)
void gemm1_mfma(const _Float16* __restrict__ xh, const float* __restrict__ b1,
                const float* __restrict__ W2, float* __restrict__ dst,
                int atomicMode)
{
    __shared__ __align__(16) float smem[2 * BUF_FLOATS];   // 67584 B: 2 staging bufs / gS

    const int t = threadIdx.x;
    const int lane = t & 63;
    const int w = t >> 6;
    const int bx = blockIdx.x;
    const int hSplit = bx & 3;          // bx%8 in {s, s+4}: each XCD serves 1 hSplit
    const int rowBlock = bx >> 2;
    const int rowBase = rowBlock * 128;

    const int mw = (w >> 1) * 64, nw = (w & 1) * 64;

    // --- staging source offsets (f16 elements rel. to xh), source-permuted
    unsigned int gofsA[4], gofsB[4];
    #pragma unroll
    for (int i = 0; i < 8; ++i) {
        const int c = i * 256 + t;          // slot 0..2047 (16 B each)
        const int tile = c >> 9;            // 0:Ah 1:Al 2:Bh 3:Bl
        const int s = c & 511;
        const int row = s >> 2;
        const int pq = s & 3;
        const int q = pq ^ (row & 3) ^ ((row >> 2) & 3);
        const unsigned int plane =
            (tile == 0) ? (unsigned int)XH_OFF :
            (tile == 1) ? (unsigned int)XL_OFF :
            (tile == 2) ? (unsigned int)W1TH_OFF : (unsigned int)W1TL_OFF;
        if (tile < 2)
            gofsA[i] = plane + (unsigned int)(rowBase + row) * kD + q * 8;
        else
            gofsB[i - 4] = plane + (unsigned int)row * kD + q * 8;
    }

    // --- frag LDS offsets (f16 elements), swizzle-aware, kt-invariant
    int aOff[2][2], bOff[2][2];
    #pragma unroll
    for (int mt = 0; mt < 2; ++mt)
        #pragma unroll
        for (int ks = 0; ks < 2; ++ks) {
            const int row = mw + mt * 32 + (lane & 31);
            const int q = (lane >> 5) + 2 * ks;
            aOff[mt][ks] = row * 32 + ((q ^ (row & 3) ^ ((row >> 2) & 3)) * 8);
        }
    #pragma unroll
    for (int nt = 0; nt < 2; ++nt)
        #pragma unroll
        for (int ks = 0; ks < 2; ++ks) {
            const int row = nw + nt * 32 + (lane & 31);
            const int q = (lane >> 5) + 2 * ks;
            bOff[nt][ks] = row * 32 + ((q ^ (row & 3) ^ ((row >> 2) & 3)) * 8);
        }

    // --- GEMM2 partial accumulators (4 rows x 8 experts per thread)
    const int g_r0 = (t >> 3) * 4;
    const int g_e0 = (t & 7) * 8;
    float lacc[4][8];
    #pragma unroll
    for (int i = 0; i < 4; ++i)
        #pragma unroll
        for (int j = 0; j < 8; ++j) lacc[i][j] = 0.0f;

    // --- stage one K-step (8 x global_load_lds_dwordx4) into buffer `buf`
    auto stage = [&](int buf, int chunk, int kt) {
        _Float16* l = (_Float16*)smem + (size_t)buf * BUF_F16;
        const unsigned int hOff =
            (unsigned int)(hSplit * (CHUNKS * 128) + chunk * 128) * kD;
        #pragma unroll
        for (int i = 0; i < 4; ++i)
            async16(xh + gofsA[i] + kt, l + ((i * 256 + t) * 8));
        #pragma unroll
        for (int i = 0; i < 4; ++i)
            async16(xh + gofsB[i] + hOff + kt, l + (((i + 4) * 256 + t) * 8));
    };

    int cur = 0;
    stage(0, 0, 0);                         // prologue prefetch

    for (int chunk = 0; chunk < CHUNKS; ++chunk) {
        const int hBase = hSplit * (CHUNKS * 128) + chunk * 128;

        f32x16 accH[2][2], accL[2][2];
        #pragma unroll
        for (int a = 0; a < 2; ++a)
            #pragma unroll
            for (int b = 0; b < 2; ++b)
                #pragma unroll
                for (int r = 0; r < 16; ++r) { accH[a][b][r] = 0.0f; accL[a][b][r] = 0.0f; }

        for (int kt = 0; kt < kD; kt += 32) {
            // issue next step's loads first; only then wait for current step's 8
            const bool isLast = (chunk == CHUNKS - 1) && (kt == kD - 32);
            if (!isLast) {
                int nc = chunk, nk = kt + 32;
                if (nk == kD) { nc = chunk + 1; nk = 0; }
                stage(cur ^ 1, nc, nk);
                asm volatile("s_waitcnt vmcnt(8)" ::: "memory");
            } else {
                asm volatile("s_waitcnt vmcnt(0)" ::: "memory");
            }
            __builtin_amdgcn_s_barrier();           // buf[cur] ready for all waves
            asm volatile("" ::: "memory");

            const _Float16* lds = (const _Float16*)smem + (size_t)cur * BUF_F16;

            half8 aH[2][2], aL[2][2], bH[2][2], bL[2][2];
            #pragma unroll
            for (int mt = 0; mt < 2; ++mt)
                #pragma unroll
                for (int ks = 0; ks < 2; ++ks) {
                    aH[mt][ks] = *reinterpret_cast<const half8*>(lds + aOff[mt][ks]);
                    aL[mt][ks] = *reinterpret_cast<const half8*>(lds + 4096 + aOff[mt][ks]);
                }
            #pragma unroll
            for (int nt = 0; nt < 2; ++nt)
                #pragma unroll
                for (int ks = 0; ks < 2; ++ks) {
                    bH[nt][ks] = *reinterpret_cast<const half8*>(lds + 8192 + bOff[nt][ks]);
                    bL[nt][ks] = *reinterpret_cast<const half8*>(lds + 12288 + bOff[nt][ks]);
                }

            #pragma unroll
            for (int ks = 0; ks < 2; ++ks)
                #pragma unroll
                for (int mt = 0; mt < 2; ++mt)
                    #pragma unroll
                    for (int nt = 0; nt < 2; ++nt) {
                        accH[mt][nt] = __builtin_amdgcn_mfma_f32_32x32x16_f16(
                            aH[mt][ks], bH[nt][ks], accH[mt][nt], 0, 0, 0);
                        accL[mt][nt] = __builtin_amdgcn_mfma_f32_32x32x16_f16(
                            aH[mt][ks], bL[nt][ks], accL[mt][nt], 0, 0, 0);
                        accL[mt][nt] = __builtin_amdgcn_mfma_f32_32x32x16_f16(
                            aL[mt][ks], bH[nt][ks], accL[mt][nt], 0, 0, 0);
                    }

            // all ds_reads of buf[cur] must land before anyone can overwrite it
            asm volatile("s_waitcnt lgkmcnt(0)" ::: "memory");
            __builtin_amdgcn_s_barrier();
            cur ^= 1;
        }

        // --- epilogue: combine + bias + gelu -> gS (g^T), GEMM2 partial.
        // gS aliases the just-read buffer; in-flight prefetch is in buf[cur].
        float* gS = smem + (size_t)(cur ^ 1) * BUF_FLOATS;
        const float inv2048 = 1.0f / 2048.0f;
        for (int hf = 0; hf < 2; ++hf) {
            asm volatile("s_waitcnt lgkmcnt(0)" ::: "memory");
            __builtin_amdgcn_s_barrier();
            asm volatile("" ::: "memory");
            if ((w & 1) == hf) {
                #pragma unroll
                for (int nt = 0; nt < 2; ++nt) {
                    const int hl = nt * 32 + (lane & 31);
                    const float bb = b1[hBase + hf * 64 + hl];
                    #pragma unroll
                    for (int mt = 0; mt < 2; ++mt) {
                        #pragma unroll
                        for (int rq = 0; rq < 4; ++rq) {
                            float vr[4];
                            #pragma unroll
                            for (int rr = 0; rr < 4; ++rr) {
                                const int r = rq * 4 + rr;
                                const float hv = accH[mt][nt][r] + accL[mt][nt][r] * inv2048 + bb;
                                vr[rr] = 0.5f * hv * (1.0f + erff(hv * 0.70710678118654752f));
                            }
                            const int mrow = mw + mt * 32 + 8 * rq + 4 * (lane >> 5);
                            *reinterpret_cast<float4*>(gS + hl * GS_STRIDE + mrow) =
                                make_float4(vr[0], vr[1], vr[2], vr[3]);
                        }
                    }
                }
            }
            asm volatile("s_waitcnt lgkmcnt(0)" ::: "memory");
            __builtin_amdgcn_s_barrier();
            asm volatile("" ::: "memory");
            const float* W2p = W2 + (size_t)(hBase + hf * 64) * kE + g_e0;
            #pragma unroll 4
            for (int h = 0; h < 64; ++h) {
                const float4 gv = *reinterpret_cast<const float4*>(gS + h * GS_STRIDE + g_r0);
                const float4 w0 = *reinterpret_cast<const float4*>(W2p + (size_t)h * kE);
                const float4 w1 = *reinterpret_cast<const float4*>(W2p + (size_t)h * kE + 4);
                const float ga[4] = {gv.x, gv.y, gv.z, gv.w};
                const float wb[8] = {w0.x, w0.y, w0.z, w0.w, w1.x, w1.y, w1.z, w1.w};
                #pragma unroll
                for (int i = 0; i < 4; ++i)
                    #pragma unroll
                    for (int j = 0; j < 8; ++j)
                        lacc[i][j] = fmaf(ga[i], wb[j], lacc[i][j]);
            }
        }
        // gS reads must land before next chunk's stage overwrites this buffer
        asm volatile("s_waitcnt lgkmcnt(0)" ::: "memory");
        __builtin_amdgcn_s_barrier();
    }

    // --- write GEMM2 partial: exclusive slice (mode 0) or atomics (mode 1)
    if (atomicMode) {
        #pragma unroll
        for (int i = 0; i < 4; ++i)
            #pragma unroll
            for (int j = 0; j < 8; ++j)
                atomicAdd(dst + (size_t)(rowBase + g_r0 + i) * kE + g_e0 + j, lacc[i][j]);
    } else {
        float* drow = dst + ((size_t)hSplit * kN + rowBase + g_r0) * kE + g_e0;
        #pragma unroll
        for (int i = 0; i < 4; ++i) {
            *reinterpret_cast<float4*>(drow + (size_t)i * kE) =
                make_float4(lacc[i][0], lacc[i][1], lacc[i][2], lacc[i][3]);
            *reinterpret_cast<float4*>(drow + (size_t)i * kE + 4) =
                make_float4(lacc[i][4], lacc[i][5], lacc[i][6], lacc[i][7]);
        }
    }
}

// ---------------------------------------------------------------------------
// Fallback fp32 GEMM1 (verified R1 kernel) — used when ws is too small
// ---------------------------------------------------------------------------
__global__ __launch_bounds__(256, 2)
void gemm1_kernel(const float* __restrict__ x, const float* __restrict__ W1,
                  const float* __restrict__ b1, const float* __restrict__ W2,
                  float* __restrict__ logits)
{
    __shared__ __align__(16) float smem[64 * GS_STRIDE];
    float* As = smem;
    float* Bs = smem + 32 * 128;
    float* gS = smem;

    const int t  = threadIdx.x;
    const int bx = blockIdx.x;
    const int rowBlock = bx >> 2;
    const int hSplit   = bx & 3;
    const int rowBase  = rowBlock * 128;
    const int hBase0   = hSplit * 1024;

    const int ty = t >> 4;
    const int tx = t & 15;
    const int r0 = ty * 8;
    const int c0 = tx * 8;
    const int g_r0 = (t >> 3) * 4;
    const int g_e0 = (t & 7) * 8;

    float lacc[4][8];
    #pragma unroll
    for (int i = 0; i < 4; ++i)
        #pragma unroll
        for (int j = 0; j < 8; ++j) lacc[i][j] = 0.0f;

    for (int chunk = 0; chunk < 8; ++chunk) {
        const int hBase = hBase0 + chunk * 128;
        float C[8][8];
        #pragma unroll
        for (int i = 0; i < 8; ++i)
            #pragma unroll
            for (int j = 0; j < 8; ++j) C[i][j] = 0.0f;

        for (int kt = 0; kt < kD; kt += 32) {
            __syncthreads();
            #pragma unroll
            for (int i = 0; i < 4; ++i) {
                const int f  = t + 256 * i;
                const int m  = f >> 3;
                const int kq = (f & 7) * 4;
                const float4 v = *reinterpret_cast<const float4*>(
                    x + (size_t)(rowBase + m) * kD + kt + kq);
                As[(kq + 0) * 128 + m] = v.x;
                As[(kq + 1) * 128 + m] = v.y;
                As[(kq + 2) * 128 + m] = v.z;
                As[(kq + 3) * 128 + m] = v.w;
            }
            #pragma unroll
            for (int i = 0; i < 4; ++i) {
                const int f  = t + 256 * i;
                const int k  = f >> 5;
                const int n4 = (f & 31) * 4;
                *reinterpret_cast<float4*>(Bs + k * 128 + n4) =
                    *reinterpret_cast<const float4*>(W1 + (size_t)(kt + k) * kH + hBase + n4);
            }
            __syncthreads();
            #pragma unroll 8
            for (int k = 0; k < 32; ++k) {
                const float4 a0 = *reinterpret_cast<const float4*>(As + k * 128 + r0);
                const float4 a1 = *reinterpret_cast<const float4*>(As + k * 128 + r0 + 4);
                const float4 b0 = *reinterpret_cast<const float4*>(Bs + k * 128 + c0);
                const float4 b1v = *reinterpret_cast<const float4*>(Bs + k * 128 + c0 + 4);
                const float a[8] = {a0.x, a0.y, a0.z, a0.w, a1.x, a1.y, a1.z, a1.w};
                const float b[8] = {b0.x, b0.y, b0.z, b0.w, b1v.x, b1v.y, b1v.z, b1v.w};
                #pragma unroll
                for (int i = 0; i < 8; ++i)
                    #pragma unroll
                    for (int j = 0; j < 8; ++j)
                        C[i][j] = fmaf(a[i], b[j], C[i][j]);
            }
        }

        #pragma unroll
        for (int j = 0; j < 8; ++j) {
            const float bb = b1[hBase + c0 + j];
            #pragma unroll
            for (int i = 0; i < 8; ++i) {
                const float hv = C[i][j] + bb;
                C[i][j] = 0.5f * hv * (1.0f + erff(hv * 0.70710678118654752f));
            }
        }

        for (int half = 0; half < 2; ++half) {
            __syncthreads();
            if ((tx >> 3) == half) {
                const int hloc0 = c0 - half * 64;
                #pragma unroll
                for (int j = 0; j < 8; ++j) {
                    const float4 col = make_float4(C[0][j], C[1][j], C[2][j], C[3][j]);
                    const float4 col2 = make_float4(C[4][j], C[5][j], C[6][j], C[7][j]);
                    *reinterpret_cast<float4*>(gS + (hloc0 + j) * GS_STRIDE + r0)     = col;
                    *reinterpret_cast<float4*>(gS + (hloc0 + j) * GS_STRIDE + r0 + 4) = col2;
                }
            }
            __syncthreads();
            const float* W2p = W2 + (size_t)(hBase + half * 64) * kE + g_e0;
            #pragma unroll 4
            for (int h = 0; h < 64; ++h) {
                const float4 gv = *reinterpret_cast<const float4*>(gS + h * GS_STRIDE + g_r0);
                const float4 w0 = *reinterpret_cast<const float4*>(W2p + (size_t)h * kE);
                const float4 w1 = *reinterpret_cast<const float4*>(W2p + (size_t)h * kE + 4);
                const float ga[4] = {gv.x, gv.y, gv.z, gv.w};
                const float wb[8] = {w0.x, w0.y, w0.z, w0.w, w1.x, w1.y, w1.z, w1.w};
                #pragma unroll
                for (int i = 0; i < 4; ++i)
                    #pragma unroll
                    for (int j = 0; j < 8; ++j)
                        lacc[i][j] = fmaf(ga[i], wb[j], lacc[i][j]);
            }
        }
    }

    #pragma unroll
    for (int i = 0; i < 4; ++i)
        #pragma unroll
        for (int j = 0; j < 8; ++j)
            atomicAdd(logits + (size_t)(rowBase + g_r0 + i) * kE + g_e0 + j, lacc[i][j]);
}

// ---------------------------------------------------------------------------
// Router: logits from partials (mode 0) or logits buffer (mode 1); softmax,
// shared split, top-2 with min-index tie-break, indices written as float.
// ---------------------------------------------------------------------------
__global__ __launch_bounds__(256)
void router_kernel(const float* __restrict__ b2, const float* __restrict__ src,
                   int atomicMode, float* __restrict__ out)
{
    const int lane = threadIdx.x & 63;
    const int row  = blockIdx.x * 4 + (threadIdx.x >> 6);

    float logit;
    if (atomicMode) {
        logit = src[(size_t)row * kE + lane] + b2[lane];
    } else {
        const float* p = src + (size_t)row * kE + lane;
        logit = p[0] + p[(size_t)kN * kE] + p[(size_t)2 * kN * kE] +
                p[(size_t)3 * kN * kE] + b2[lane];
    }

    float m = logit;
    #pragma unroll
    for (int off = 32; off > 0; off >>= 1) m = fmaxf(m, __shfl_xor(m, off));
    const float p = expf(logit - m);
    float s = p;
    #pragma unroll
    for (int off = 32; off > 0; off >>= 1) s += __shfl_xor(s, off);
    const float w = p / s;

    out[OFF_W + (size_t)row * kE + lane] = w;
    if (lane < kShared) out[OFF_GW + (size_t)row * kShared + lane] = w;

    float v1 = (lane >= kShared) ? w : -1.0f;
    int   i1 = lane - kShared;
    #pragma unroll
    for (int off = 32; off > 0; off >>= 1) {
        const float ov = __shfl_xor(v1, off);
        const int   oi = __shfl_xor(i1, off);
        if (ov > v1 || (ov == v1 && oi < i1)) { v1 = ov; i1 = oi; }
    }
    float v2 = (lane >= kShared && (lane - kShared) != i1) ? w : -1.0f;
    int   i2 = lane - kShared;
    #pragma unroll
    for (int off = 32; off > 0; off >>= 1) {
        const float ov = __shfl_xor(v2, off);
        const int   oi = __shfl_xor(i2, off);
        if (ov > v2 || (ov == v2 && oi < i2)) { v2 = ov; i2 = oi; }
    }
    if (lane == 0) {
        out[OFF_LW + (size_t)row * 2 + 0] = v1;
        out[OFF_LW + (size_t)row * 2 + 1] = v2;
        out[OFF_LI + (size_t)row * 2 + 0] = (float)i1;
        out[OFF_LI + (size_t)row * 2 + 1] = (float)i2;
    }
}

extern "C" void kernel_launch(void* const* d_in, const int* in_sizes, int n_in,
                              void* d_out, int out_size, void* d_ws, size_t ws_size,
                              hipStream_t stream)
{
    const float* x  = (const float*)d_in[0];
    const float* W1 = (const float*)d_in[1];
    const float* b1 = (const float*)d_in[2];
    const float* W2 = (const float*)d_in[3];
    const float* b2 = (const float*)d_in[4];
    float* out = (float*)d_out;
    float* logits = out + OFF_W;

    if (ws_size >= WS_BASE) {
        _Float16* base = (_Float16*)d_ws;
        const int atomicMode = (ws_size >= WS_FULL) ? 0 : 1;
        float* dst = atomicMode ? logits : ((float*)d_ws + PART_FLOAT_OFF);
        if (atomicMode)
            hipMemsetAsync(logits, 0, (size_t)kN * kE * sizeof(float), stream);
        hipLaunchKernelGGL(convert_x, dim3(kN * kD / 1024), dim3(256), 0, stream,
                           x, base + XH_OFF, base + XL_OFF);
        hipLaunchKernelGGL(convert_w1t, dim3((kD / 64) * (kH / 64)), dim3(256), 0, stream,
                           W1, base + W1TH_OFF, base + W1TL_OFF);
        hipLaunchKernelGGL(gemm1_mfma, dim3((kN / 128) * HSPLIT), dim3(256), 0, stream,
                           base + XH_OFF, b1, W2, dst, atomicMode);
        hipLaunchKernelGGL(router_kernel, dim3(kN / 4), dim3(256), 0, stream,
                           b2, dst, atomicMode, out);
    } else {
        hipMemsetAsync(logits, 0, (size_t)kN * kE * sizeof(float), stream);
        hipLaunchKernelGGL(gemm1_kernel, dim3((kN / 128) * 4), dim3(256), 0, stream,
                           x, W1, b1, W2, logits);
        hipLaunchKernelGGL(router_kernel, dim3(kN / 4), dim3(256), 0, stream,
                           b2, logits, 1, out);
    }
}

// Round 2
// 1246.520 us; speedup vs baseline: 1.0488x; 1.0360x over previous
//
#include <hip/hip_runtime.h>
#include <math.h>

namespace {
constexpr int kN = 16384;
constexpr int kD = 2048;
constexpr int kH = 4096;
constexpr int kE = 64;
constexpr int kShared = 8;

// d_out layout (floats), reference return order
constexpr int OFF_GW = 0;                       // global_weights: N x 8
constexpr int OFF_LW = kN * kShared;            // local_weights:  N x 2
constexpr int OFF_LI = OFF_LW + kN * 2;         // local_indices:  N x 2 (as float)
constexpr int OFF_W  = OFF_LI + kN * 2;         // weights: N x 64 -- logit accumulator in atomic mode

constexpr int GS_STRIDE = 132;
constexpr int HSPLIT = 4;
constexpr int CHUNKS = 8;       // 8 x 128 = 1024 H-cols per block

// workspace layout (f16 elements from base)
constexpr size_t XH_OFF  = 0;
constexpr size_t XL_OFF  = (size_t)kN * kD;
constexpr size_t W1TH_OFF = XL_OFF + (size_t)kN * kD;
constexpr size_t W1TL_OFF = W1TH_OFF + (size_t)kH * kD;
constexpr size_t WS_BASE = (W1TL_OFF + (size_t)kH * kD) * 2;          // bytes: 167,772,160
constexpr size_t PART_FLOAT_OFF = WS_BASE / 4;                         // float index of partials
constexpr size_t WS_FULL = WS_BASE + (size_t)HSPLIT * kN * kE * 4;     // + 16.8 MB partials

// double-buffer geometry (f16 elements per buffer region)
constexpr int BUF_FLOATS = 64 * GS_STRIDE;      // 8448 floats = 33792 B per buffer
constexpr int BUF_F16    = BUF_FLOATS * 2;      // 16896 f16 slots (staging uses first 16384)
}

typedef _Float16 half8  __attribute__((ext_vector_type(8)));
typedef _Float16 half4t __attribute__((ext_vector_type(4)));
typedef float    f32x16 __attribute__((ext_vector_type(16)));

__device__ __forceinline__ void async16(const _Float16* g, _Float16* l) {
    __builtin_amdgcn_global_load_lds(
        (const __attribute__((address_space(1))) void*)g,
        (__attribute__((address_space(3))) void*)l, 16, 0, 0);
}

// ---------------------------------------------------------------------------
// Pre-pass 1: x (fp32) -> xh, xl (f16 planes; xl pre-scaled by 2048)
// ---------------------------------------------------------------------------
__global__ __launch_bounds__(256)
void convert_x(const float* __restrict__ x, _Float16* __restrict__ xh,
               _Float16* __restrict__ xl)
{
    const size_t i = ((size_t)blockIdx.x * 256 + threadIdx.x) * 4;
    const float4 v = *reinterpret_cast<const float4*>(x + i);
    half4t h, l;
    const float vs[4] = {v.x, v.y, v.z, v.w};
    #pragma unroll
    for (int j = 0; j < 4; ++j) {
        const _Float16 hj = (_Float16)vs[j];
        h[j] = hj;
        l[j] = (_Float16)((vs[j] - (float)hj) * 2048.0f);
    }
    *reinterpret_cast<half4t*>(xh + i) = h;
    *reinterpret_cast<half4t*>(xl + i) = l;
}

// ---------------------------------------------------------------------------
// Pre-pass 2: W1 [D][H] fp32 -> W1^T hi/lo planes [H][D] f16 (lo scaled 2048)
// ---------------------------------------------------------------------------
__global__ __launch_bounds__(256)
void convert_w1t(const float* __restrict__ W1, _Float16* __restrict__ th,
                 _Float16* __restrict__ tl)
{
    __shared__ float T[64][65];
    const int bk = blockIdx.x & 31;
    const int bn = blockIdx.x >> 5;
    const int k0 = bk * 64, n0 = bn * 64;
    const int t = threadIdx.x;
    const int c4 = (t & 15) * 4, r = t >> 4;

    #pragma unroll
    for (int i = 0; i < 4; ++i) {
        const int kk = r + 16 * i;
        const float4 v = *reinterpret_cast<const float4*>(
            W1 + (size_t)(k0 + kk) * kH + n0 + c4);
        T[kk][c4 + 0] = v.x; T[kk][c4 + 1] = v.y;
        T[kk][c4 + 2] = v.z; T[kk][c4 + 3] = v.w;
    }
    __syncthreads();
    #pragma unroll
    for (int i = 0; i < 4; ++i) {
        const int nn = r + 16 * i;
        half4t h, l;
        #pragma unroll
        for (int j = 0; j < 4; ++j) {
            const float vv = T[c4 + j][nn];
            const _Float16 hj = (_Float16)vv;
            h[j] = hj;
            l[j] = (_Float16)((vv - (float)hj) * 2048.0f);
        }
        *reinterpret_cast<half4t*>(th + (size_t)(n0 + nn) * kD + k0 + c4) = h;
        *reinterpret_cast<half4t*>(tl + (size_t)(n0 + nn) * kD + k0 + c4) = l;
    }
}

// ---------------------------------------------------------------------------
// GEMM1 split-f16 3-pass MFMA, fused gelu + GEMM2 partial.
// grid = 512 (hSplit = bx&3 -> per-XCD W1 locality), block = 256 (4 waves).
//
// R2: 2-sub-phase K-step (minimum T3 form) + T5 setprio + de-serialized
// epilogue.
//  - Per K-step: {stageA(4); vmcnt(4); BAR; read ks0 frags; prio1 12-MFMA
//    prio0; BAR; read ks1 frags + stageB(4); prio1 12-MFMA prio0; lgkm0 BAR}.
//    Loads for buf[c_{t+1}] stay in flight across the whole step (counted
//    vmcnt(4) at t+1 entry, never 0 in the main loop).
//  - Wave nt-tiles remapped to cols nt*64 + (w&1)*32: every wave owns 32
//    columns in EACH hf half, so all 4 waves gelu+write gS concurrently in
//    both epilogue passes (was 2-of-4 -> SIMD idling).
// LDS staging keeps the source-permuted chunk swizzle:
// logical chunk q of row r lives at physical chunk q ^ (r&3) ^ ((r>>2)&3).
// ---------------------------------------------------------------------------
__global__ __launch_bounds__(256, 2)
void gemm1_mfma(const _Float16* __restrict__ xh, const float* __restrict__ b1,
                const float* __restrict__ W2, float* __restrict__ dst,
                int atomicMode)
{
    __shared__ __align__(16) float smem[2 * BUF_FLOATS];   // 67584 B: 2 staging bufs / gS

    const int t = threadIdx.x;
    const int lane = t & 63;
    const int w = t >> 6;
    const int bx = blockIdx.x;
    const int hSplit = bx & 3;          // bx%8 in {s, s+4}: each XCD serves 1 hSplit
    const int rowBlock = bx >> 2;
    const int rowBase = rowBlock * 128;

    const int mw = (w >> 1) * 64;
    const int nc32 = (w & 1) * 32;      // column sub-offset within each 64-col half

    // --- staging source offsets (f16 elements rel. to xh), source-permuted
    unsigned int gofsA[4], gofsB[4];
    #pragma unroll
    for (int i = 0; i < 8; ++i) {
        const int c = i * 256 + t;          // slot 0..2047 (16 B each)
        const int tile = c >> 9;            // 0:Ah 1:Al 2:Bh 3:Bl
        const int s = c & 511;
        const int row = s >> 2;
        const int pq = s & 3;
        const int q = pq ^ (row & 3) ^ ((row >> 2) & 3);
        const unsigned int plane =
            (tile == 0) ? (unsigned int)XH_OFF :
            (tile == 1) ? (unsigned int)XL_OFF :
            (tile == 2) ? (unsigned int)W1TH_OFF : (unsigned int)W1TL_OFF;
        if (tile < 2)
            gofsA[i] = plane + (unsigned int)(rowBase + row) * kD + q * 8;
        else
            gofsB[i - 4] = plane + (unsigned int)row * kD + q * 8;
    }

    // --- frag LDS offsets (f16 elements), swizzle-aware, kt-invariant
    int aOff[2][2], bOff[2][2];
    #pragma unroll
    for (int mt = 0; mt < 2; ++mt)
        #pragma unroll
        for (int ks = 0; ks < 2; ++ks) {
            const int row = mw + mt * 32 + (lane & 31);
            const int q = (lane >> 5) + 2 * ks;
            aOff[mt][ks] = row * 32 + ((q ^ (row & 3) ^ ((row >> 2) & 3)) * 8);
        }
    #pragma unroll
    for (int nt = 0; nt < 2; ++nt)
        #pragma unroll
        for (int ks = 0; ks < 2; ++ks) {
            const int row = nt * 64 + nc32 + (lane & 31);   // interleaved nt->col map
            const int q = (lane >> 5) + 2 * ks;
            bOff[nt][ks] = row * 32 + ((q ^ (row & 3) ^ ((row >> 2) & 3)) * 8);
        }

    // --- GEMM2 partial accumulators (4 rows x 8 experts per thread)
    const int g_r0 = (t >> 3) * 4;
    const int g_e0 = (t & 7) * 8;
    float lacc[4][8];
    #pragma unroll
    for (int i = 0; i < 4; ++i)
        #pragma unroll
        for (int j = 0; j < 8; ++j) lacc[i][j] = 0.0f;

    // --- staging halves: A planes (4 loads) / B planes (4 loads)
    auto stageA = [&](int buf, int nk) {
        _Float16* l = (_Float16*)smem + (size_t)buf * BUF_F16;
        #pragma unroll
        for (int i = 0; i < 4; ++i)
            async16(xh + gofsA[i] + nk, l + ((i * 256 + t) * 8));
    };
    auto stageB = [&](int buf, int nc, int nk) {
        _Float16* l = (_Float16*)smem + (size_t)buf * BUF_F16;
        const unsigned int hOff =
            (unsigned int)(hSplit * (CHUNKS * 128) + nc * 128) * kD;
        #pragma unroll
        for (int i = 0; i < 4; ++i)
            async16(xh + gofsB[i] + hOff + nk, l + (((i + 4) * 256 + t) * 8));
    };

    int cur = 0;
    stageA(0, 0);                       // prologue prefetch (chunk 0, kt 0)
    stageB(0, 0, 0);

    for (int chunk = 0; chunk < CHUNKS; ++chunk) {
        const int hBase = hSplit * (CHUNKS * 128) + chunk * 128;

        f32x16 accH[2][2], accL[2][2];
        #pragma unroll
        for (int a = 0; a < 2; ++a)
            #pragma unroll
            for (int b = 0; b < 2; ++b)
                #pragma unroll
                for (int r = 0; r < 16; ++r) { accH[a][b][r] = 0.0f; accL[a][b][r] = 0.0f; }

        for (int kt = 0; kt < kD; kt += 32) {
            const bool isLast = (chunk == CHUNKS - 1) && (kt == kD - 32);
            int nc = chunk, nk = kt + 32;
            if (nk == kD) { nc = chunk + 1; nk = 0; }

            const _Float16* lds = (const _Float16*)smem + (size_t)cur * BUF_F16;
            const int nbuf = cur ^ 1;

            if (!isLast) {
                stageA(nbuf, nk);                       // issue next-step A loads
                asm volatile("s_waitcnt vmcnt(4)" ::: "memory");  // prev step's 8 done
            } else {
                asm volatile("s_waitcnt vmcnt(0)" ::: "memory");
            }
            __builtin_amdgcn_s_barrier();               // B1: buf[cur] ready for all
            asm volatile("" ::: "memory");

            // ---- P0: ks = 0 --------------------------------------------------
            {
                half8 aH[2], aL[2], bH[2], bL[2];
                #pragma unroll
                for (int mt = 0; mt < 2; ++mt) {
                    aH[mt] = *reinterpret_cast<const half8*>(lds + aOff[mt][0]);
                    aL[mt] = *reinterpret_cast<const half8*>(lds + 4096 + aOff[mt][0]);
                }
                #pragma unroll
                for (int nt = 0; nt < 2; ++nt) {
                    bH[nt] = *reinterpret_cast<const half8*>(lds + 8192 + bOff[nt][0]);
                    bL[nt] = *reinterpret_cast<const half8*>(lds + 12288 + bOff[nt][0]);
                }
                __builtin_amdgcn_s_setprio(1);
                #pragma unroll
                for (int mt = 0; mt < 2; ++mt)
                    #pragma unroll
                    for (int nt = 0; nt < 2; ++nt) {
                        accH[mt][nt] = __builtin_amdgcn_mfma_f32_32x32x16_f16(
                            aH[mt], bH[nt], accH[mt][nt], 0, 0, 0);
                        accL[mt][nt] = __builtin_amdgcn_mfma_f32_32x32x16_f16(
                            aH[mt], bL[nt], accL[mt][nt], 0, 0, 0);
                        accL[mt][nt] = __builtin_amdgcn_mfma_f32_32x32x16_f16(
                            aL[mt], bH[nt], accL[mt][nt], 0, 0, 0);
                    }
                __builtin_amdgcn_s_setprio(0);
                __builtin_amdgcn_sched_barrier(0);      // keep cluster in its phase
            }
            asm volatile("" ::: "memory");
            __builtin_amdgcn_s_barrier();               // B2: phase split
            asm volatile("" ::: "memory");

            // ---- P1: ks = 1 --------------------------------------------------
            {
                half8 aH[2], aL[2], bH[2], bL[2];
                #pragma unroll
                for (int mt = 0; mt < 2; ++mt) {
                    aH[mt] = *reinterpret_cast<const half8*>(lds + aOff[mt][1]);
                    aL[mt] = *reinterpret_cast<const half8*>(lds + 4096 + aOff[mt][1]);
                }
                #pragma unroll
                for (int nt = 0; nt < 2; ++nt) {
                    bH[nt] = *reinterpret_cast<const half8*>(lds + 8192 + bOff[nt][1]);
                    bL[nt] = *reinterpret_cast<const half8*>(lds + 12288 + bOff[nt][1]);
                }
                if (!isLast) stageB(nbuf, nc, nk);      // issue next-step B loads
                __builtin_amdgcn_s_setprio(1);
                #pragma unroll
                for (int mt = 0; mt < 2; ++mt)
                    #pragma unroll
                    for (int nt = 0; nt < 2; ++nt) {
                        accH[mt][nt] = __builtin_amdgcn_mfma_f32_32x32x16_f16(
                            aH[mt], bH[nt], accH[mt][nt], 0, 0, 0);
                        accL[mt][nt] = __builtin_amdgcn_mfma_f32_32x32x16_f16(
                            aH[mt], bL[nt], accL[mt][nt], 0, 0, 0);
                        accL[mt][nt] = __builtin_amdgcn_mfma_f32_32x32x16_f16(
                            aL[mt], bH[nt], accL[mt][nt], 0, 0, 0);
                    }
                __builtin_amdgcn_s_setprio(0);
                __builtin_amdgcn_sched_barrier(0);
            }
            asm volatile("s_waitcnt lgkmcnt(0)" ::: "memory");
            __builtin_amdgcn_s_barrier();               // B3: close step
            asm volatile("" ::: "memory");
            cur ^= 1;
        }

        // --- epilogue: combine + bias + gelu -> gS (g^T), GEMM2 partial.
        // gS aliases the just-read buffer; in-flight prefetch is in buf[cur].
        // All 4 waves participate in BOTH hf passes (interleaved nt->col map).
        float* gS = smem + (size_t)(cur ^ 1) * BUF_FLOATS;
        const float inv2048 = 1.0f / 2048.0f;
        const int hl = nc32 + (lane & 31);
        for (int hf = 0; hf < 2; ++hf) {
            if (hf) {   // GEMM2(hf=0) reads of gS must land before overwrite
                asm volatile("s_waitcnt lgkmcnt(0)" ::: "memory");
                __builtin_amdgcn_s_barrier();
                asm volatile("" ::: "memory");
            }
            const float bb = b1[hBase + hf * 64 + hl];
            #pragma unroll
            for (int mt = 0; mt < 2; ++mt) {
                #pragma unroll
                for (int rq = 0; rq < 4; ++rq) {
                    float vr[4];
                    #pragma unroll
                    for (int rr = 0; rr < 4; ++rr) {
                        const int r = rq * 4 + rr;
                        const float hv = accH[mt][hf][r] + accL[mt][hf][r] * inv2048 + bb;
                        vr[rr] = 0.5f * hv * (1.0f + erff(hv * 0.70710678118654752f));
                    }
                    const int mrow = mw + mt * 32 + 8 * rq + 4 * (lane >> 5);
                    *reinterpret_cast<float4*>(gS + hl * GS_STRIDE + mrow) =
                        make_float4(vr[0], vr[1], vr[2], vr[3]);
                }
            }
            asm volatile("s_waitcnt lgkmcnt(0)" ::: "memory");
            __builtin_amdgcn_s_barrier();
            asm volatile("" ::: "memory");
            const float* W2p = W2 + (size_t)(hBase + hf * 64) * kE + g_e0;
            #pragma unroll 4
            for (int h = 0; h < 64; ++h) {
                const float4 gv = *reinterpret_cast<const float4*>(gS + h * GS_STRIDE + g_r0);
                const float4 w0 = *reinterpret_cast<const float4*>(W2p + (size_t)h * kE);
                const float4 w1 = *reinterpret_cast<const float4*>(W2p + (size_t)h * kE + 4);
                const float ga[4] = {gv.x, gv.y, gv.z, gv.w};
                const float wb[8] = {w0.x, w0.y, w0.z, w0.w, w1.x, w1.y, w1.z, w1.w};
                #pragma unroll
                for (int i = 0; i < 4; ++i)
                    #pragma unroll
                    for (int j = 0; j < 8; ++j)
                        lacc[i][j] = fmaf(ga[i], wb[j], lacc[i][j]);
            }
        }
        // gS reads must land before next chunk's stage overwrites this buffer
        asm volatile("s_waitcnt lgkmcnt(0)" ::: "memory");
        __builtin_amdgcn_s_barrier();
        asm volatile("" ::: "memory");
    }

    // --- write GEMM2 partial: exclusive slice (mode 0) or atomics (mode 1)
    if (atomicMode) {
        #pragma unroll
        for (int i = 0; i < 4; ++i)
            #pragma unroll
            for (int j = 0; j < 8; ++j)
                atomicAdd(dst + (size_t)(rowBase + g_r0 + i) * kE + g_e0 + j, lacc[i][j]);
    } else {
        float* drow = dst + ((size_t)hSplit * kN + rowBase + g_r0) * kE + g_e0;
        #pragma unroll
        for (int i = 0; i < 4; ++i) {
            *reinterpret_cast<float4*>(drow + (size_t)i * kE) =
                make_float4(lacc[i][0], lacc[i][1], lacc[i][2], lacc[i][3]);
            *reinterpret_cast<float4*>(drow + (size_t)i * kE + 4) =
                make_float4(lacc[i][4], lacc[i][5], lacc[i][6], lacc[i][7]);
        }
    }
}

// ---------------------------------------------------------------------------
// Fallback fp32 GEMM1 (verified R1 kernel) — used when ws is too small
// ---------------------------------------------------------------------------
__global__ __launch_bounds__(256, 2)
void gemm1_kernel(const float* __restrict__ x, const float* __restrict__ W1,
                  const float* __restrict__ b1, const float* __restrict__ W2,
                  float* __restrict__ logits)
{
    __shared__ __align__(16) float smem[64 * GS_STRIDE];
    float* As = smem;
    float* Bs = smem + 32 * 128;
    float* gS = smem;

    const int t  = threadIdx.x;
    const int bx = blockIdx.x;
    const int rowBlock = bx >> 2;
    const int hSplit   = bx & 3;
    const int rowBase  = rowBlock * 128;
    const int hBase0   = hSplit * 1024;

    const int ty = t >> 4;
    const int tx = t & 15;
    const int r0 = ty * 8;
    const int c0 = tx * 8;
    const int g_r0 = (t >> 3) * 4;
    const int g_e0 = (t & 7) * 8;

    float lacc[4][8];
    #pragma unroll
    for (int i = 0; i < 4; ++i)
        #pragma unroll
        for (int j = 0; j < 8; ++j) lacc[i][j] = 0.0f;

    for (int chunk = 0; chunk < 8; ++chunk) {
        const int hBase = hBase0 + chunk * 128;
        float C[8][8];
        #pragma unroll
        for (int i = 0; i < 8; ++i)
            #pragma unroll
            for (int j = 0; j < 8; ++j) C[i][j] = 0.0f;

        for (int kt = 0; kt < kD; kt += 32) {
            __syncthreads();
            #pragma unroll
            for (int i = 0; i < 4; ++i) {
                const int f  = t + 256 * i;
                const int m  = f >> 3;
                const int kq = (f & 7) * 4;
                const float4 v = *reinterpret_cast<const float4*>(
                    x + (size_t)(rowBase + m) * kD + kt + kq);
                As[(kq + 0) * 128 + m] = v.x;
                As[(kq + 1) * 128 + m] = v.y;
                As[(kq + 2) * 128 + m] = v.z;
                As[(kq + 3) * 128 + m] = v.w;
            }
            #pragma unroll
            for (int i = 0; i < 4; ++i) {
                const int f  = t + 256 * i;
                const int k  = f >> 5;
                const int n4 = (f & 31) * 4;
                *reinterpret_cast<float4*>(Bs + k * 128 + n4) =
                    *reinterpret_cast<const float4*>(W1 + (size_t)(kt + k) * kH + hBase + n4);
            }
            __syncthreads();
            #pragma unroll 8
            for (int k = 0; k < 32; ++k) {
                const float4 a0 = *reinterpret_cast<const float4*>(As + k * 128 + r0);
                const float4 a1 = *reinterpret_cast<const float4*>(As + k * 128 + r0 + 4);
                const float4 b0 = *reinterpret_cast<const float4*>(Bs + k * 128 + c0);
                const float4 b1v = *reinterpret_cast<const float4*>(Bs + k * 128 + c0 + 4);
                const float a[8] = {a0.x, a0.y, a0.z, a0.w, a1.x, a1.y, a1.z, a1.w};
                const float b[8] = {b0.x, b0.y, b0.z, b0.w, b1v.x, b1v.y, b1v.z, b1v.w};
                #pragma unroll
                for (int i = 0; i < 8; ++i)
                    #pragma unroll
                    for (int j = 0; j < 8; ++j)
                        C[i][j] = fmaf(a[i], b[j], C[i][j]);
            }
        }

        #pragma unroll
        for (int j = 0; j < 8; ++j) {
            const float bb = b1[hBase + c0 + j];
            #pragma unroll
            for (int i = 0; i < 8; ++i) {
                const float hv = C[i][j] + bb;
                C[i][j] = 0.5f * hv * (1.0f + erff(hv * 0.70710678118654752f));
            }
        }

        for (int half = 0; half < 2; ++half) {
            __syncthreads();
            if ((tx >> 3) == half) {
                const int hloc0 = c0 - half * 64;
                #pragma unroll
                for (int j = 0; j < 8; ++j) {
                    const float4 col = make_float4(C[0][j], C[1][j], C[2][j], C[3][j]);
                    const float4 col2 = make_float4(C[4][j], C[5][j], C[6][j], C[7][j]);
                    *reinterpret_cast<float4*>(gS + (hloc0 + j) * GS_STRIDE + r0)     = col;
                    *reinterpret_cast<float4*>(gS + (hloc0 + j) * GS_STRIDE + r0 + 4) = col2;
                }
            }
            __syncthreads();
            const float* W2p = W2 + (size_t)(hBase + half * 64) * kE + g_e0;
            #pragma unroll 4
            for (int h = 0; h < 64; ++h) {
                const float4 gv = *reinterpret_cast<const float4*>(gS + h * GS_STRIDE + g_r0);
                const float4 w0 = *reinterpret_cast<const float4*>(W2p + (size_t)h * kE);
                const float4 w1 = *reinterpret_cast<const float4*>(W2p + (size_t)h * kE + 4);
                const float ga[4] = {gv.x, gv.y, gv.z, gv.w};
                const float wb[8] = {w0.x, w0.y, w0.z, w0.w, w1.x, w1.y, w1.z, w1.w};
                #pragma unroll
                for (int i = 0; i < 4; ++i)
                    #pragma unroll
                    for (int j = 0; j < 8; ++j)
                        lacc[i][j] = fmaf(ga[i], wb[j], lacc[i][j]);
            }
        }
    }

    #pragma unroll
    for (int i = 0; i < 4; ++i)
        #pragma unroll
        for (int j = 0; j < 8; ++j)
            atomicAdd(logits + (size_t)(rowBase + g_r0 + i) * kE + g_e0 + j, lacc[i][j]);
}

// ---------------------------------------------------------------------------
// Router: logits from partials (mode 0) or logits buffer (mode 1); softmax,
// shared split, top-2 with min-index tie-break, indices written as float.
// ---------------------------------------------------------------------------
__global__ __launch_bounds__(256)
void router_kernel(const float* __restrict__ b2, const float* __restrict__ src,
                   int atomicMode, float* __restrict__ out)
{
    const int lane = threadIdx.x & 63;
    const int row  = blockIdx.x * 4 + (threadIdx.x >> 6);

    float logit;
    if (atomicMode) {
        logit = src[(size_t)row * kE + lane] + b2[lane];
    } else {
        const float* p = src + (size_t)row * kE + lane;
        logit = p[0] + p[(size_t)kN * kE] + p[(size_t)2 * kN * kE] +
                p[(size_t)3 * kN * kE] + b2[lane];
    }

    float m = logit;
    #pragma unroll
    for (int off = 32; off > 0; off >>= 1) m = fmaxf(m, __shfl_xor(m, off));
    const float p = expf(logit - m);
    float s = p;
    #pragma unroll
    for (int off = 32; off > 0; off >>= 1) s += __shfl_xor(s, off);
    const float w = p / s;

    out[OFF_W + (size_t)row * kE + lane] = w;
    if (lane < kShared) out[OFF_GW + (size_t)row * kShared + lane] = w;

    float v1 = (lane >= kShared) ? w : -1.0f;
    int   i1 = lane - kShared;
    #pragma unroll
    for (int off = 32; off > 0; off >>= 1) {
        const float ov = __shfl_xor(v1, off);
        const int   oi = __shfl_xor(i1, off);
        if (ov > v1 || (ov == v1 && oi < i1)) { v1 = ov; i1 = oi; }
    }
    float v2 = (lane >= kShared && (lane - kShared) != i1) ? w : -1.0f;
    int   i2 = lane - kShared;
    #pragma unroll
    for (int off = 32; off > 0; off >>= 1) {
        const float ov = __shfl_xor(v2, off);
        const int   oi = __shfl_xor(i2, off);
        if (ov > v2 || (ov == v2 && oi < i2)) { v2 = ov; i2 = oi; }
    }
    if (lane == 0) {
        out[OFF_LW + (size_t)row * 2 + 0] = v1;
        out[OFF_LW + (size_t)row * 2 + 1] = v2;
        out[OFF_LI + (size_t)row * 2 + 0] = (float)i1;
        out[OFF_LI + (size_t)row * 2 + 1] = (float)i2;
    }
}

extern "C" void kernel_launch(void* const* d_in, const int* in_sizes, int n_in,
                              void* d_out, int out_size, void* d_ws, size_t ws_size,
                              hipStream_t stream)
{
    const float* x  = (const float*)d_in[0];
    const float* W1 = (const float*)d_in[1];
    const float* b1 = (const float*)d_in[2];
    const float* W2 = (const float*)d_in[3];
    const float* b2 = (const float*)d_in[4];
    float* out = (float*)d_out;
    float* logits = out + OFF_W;

    if (ws_size >= WS_BASE) {
        _Float16* base = (_Float16*)d_ws;
        const int atomicMode = (ws_size >= WS_FULL) ? 0 : 1;
        float* dst = atomicMode ? logits : ((float*)d_ws + PART_FLOAT_OFF);
        if (atomicMode)
            hipMemsetAsync(logits, 0, (size_t)kN * kE * sizeof(float), stream);
        hipLaunchKernelGGL(convert_x, dim3(kN * kD / 1024), dim3(256), 0, stream,
                           x, base + XH_OFF, base + XL_OFF);
        hipLaunchKernelGGL(convert_w1t, dim3((kD / 64) * (kH / 64)), dim3(256), 0, stream,
                           W1, base + W1TH_OFF, base + W1TL_OFF);
        hipLaunchKernelGGL(gemm1_mfma, dim3((kN / 128) * HSPLIT), dim3(256), 0, stream,
                           base + XH_OFF, b1, W2, dst, atomicMode);
        hipLaunchKernelGGL(router_kernel, dim3(kN / 4), dim3(256), 0, stream,
                           b2, dst, atomicMode, out);
    } else {
        hipMemsetAsync(logits, 0, (size_t)kN * kE * sizeof(float), stream);
        hipLaunchKernelGGL(gemm1_kernel, dim3((kN / 128) * 4), dim3(256), 0, stream,
                           x, W1, b1, W2, logits);
        hipLaunchKernelGGL(router_kernel, dim3(kN / 4), dim3(256), 0, stream,
                           b2, logits, 1, out);
    }
}

// Round 3
// 1224.775 us; speedup vs baseline: 1.0675x; 1.0178x over previous
//
#include <hip/hip_runtime.h>
#include <math.h>

namespace {
constexpr int kN = 16384;
constexpr int kD = 2048;
constexpr int kH = 4096;
constexpr int kE = 64;
constexpr int kShared = 8;

// d_out layout (floats), reference return order
constexpr int OFF_GW = 0;                       // global_weights: N x 8
constexpr int OFF_LW = kN * kShared;            // local_weights:  N x 2
constexpr int OFF_LI = OFF_LW + kN * 2;         // local_indices:  N x 2 (as float)
constexpr int OFF_W  = OFF_LI + kN * 2;         // weights: N x 64 -- logit accumulator in atomic mode

constexpr int GS_STRIDE = 132;
constexpr int HSPLIT = 4;
constexpr int CHUNKS = 8;       // 8 x 128 = 1024 H-cols per block

// workspace layout (f16 elements from base)
constexpr size_t XH_OFF  = 0;
constexpr size_t XL_OFF  = (size_t)kN * kD;
constexpr size_t W1TH_OFF = XL_OFF + (size_t)kN * kD;
constexpr size_t W1TL_OFF = W1TH_OFF + (size_t)kH * kD;
constexpr size_t WS_BASE = (W1TL_OFF + (size_t)kH * kD) * 2;          // bytes: 167,772,160
constexpr size_t PART_FLOAT_OFF = WS_BASE / 4;                         // float index of partials
constexpr size_t WS_FULL = WS_BASE + (size_t)HSPLIT * kN * kE * 4;     // + 16.8 MB partials

// double-buffer geometry (f16 elements per buffer region)
constexpr int BUF_FLOATS = 64 * GS_STRIDE;      // 8448 floats = 33792 B per buffer
constexpr int BUF_F16    = BUF_FLOATS * 2;      // 16896 f16 slots (staging uses first 16384)

constexpr int CXB = 8192;                       // convert_x blocks (4 float4/thread)
}

typedef _Float16 half8  __attribute__((ext_vector_type(8)));
typedef _Float16 half4t __attribute__((ext_vector_type(4)));
typedef float    f32x16 __attribute__((ext_vector_type(16)));

__device__ __forceinline__ void async16(const _Float16* g, _Float16* l) {
    __builtin_amdgcn_global_load_lds(
        (const __attribute__((address_space(1))) void*)g,
        (__attribute__((address_space(3))) void*)l, 16, 0, 0);
}

// ---------------------------------------------------------------------------
// Fused pre-pass: blocks [0,CXB): x (fp32) -> xh, xl (f16 planes; xl scaled
// 2048), 4 float4 per thread.  Blocks [CXB, CXB+2048): W1 [D][H] fp32 ->
// W1^T hi/lo planes [H][D] f16 (lo scaled 2048).
// ---------------------------------------------------------------------------
__global__ __launch_bounds__(256)
void convert_xw(const float* __restrict__ x, _Float16* __restrict__ xh,
                _Float16* __restrict__ xl,
                const float* __restrict__ W1, _Float16* __restrict__ th,
                _Float16* __restrict__ tl)
{
    __shared__ float T[64][65];
    const int b = blockIdx.x;
    const int t = threadIdx.x;

    if (b < CXB) {
        #pragma unroll
        for (int it = 0; it < 4; ++it) {
            const size_t i = (((size_t)it * CXB + b) * 256 + t) * 4;
            const float4 v = *reinterpret_cast<const float4*>(x + i);
            half4t h, l;
            const float vs[4] = {v.x, v.y, v.z, v.w};
            #pragma unroll
            for (int j = 0; j < 4; ++j) {
                const _Float16 hj = (_Float16)vs[j];
                h[j] = hj;
                l[j] = (_Float16)((vs[j] - (float)hj) * 2048.0f);
            }
            *reinterpret_cast<half4t*>(xh + i) = h;
            *reinterpret_cast<half4t*>(xl + i) = l;
        }
        return;
    }

    const int bb = b - CXB;
    const int bk = bb & 31;
    const int bn = bb >> 5;
    const int k0 = bk * 64, n0 = bn * 64;
    const int c4 = (t & 15) * 4, r = t >> 4;

    #pragma unroll
    for (int i = 0; i < 4; ++i) {
        const int kk = r + 16 * i;
        const float4 v = *reinterpret_cast<const float4*>(
            W1 + (size_t)(k0 + kk) * kH + n0 + c4);
        T[kk][c4 + 0] = v.x; T[kk][c4 + 1] = v.y;
        T[kk][c4 + 2] = v.z; T[kk][c4 + 3] = v.w;
    }
    __syncthreads();
    #pragma unroll
    for (int i = 0; i < 4; ++i) {
        const int nn = r + 16 * i;
        half4t h, l;
        #pragma unroll
        for (int j = 0; j < 4; ++j) {
            const float vv = T[c4 + j][nn];
            const _Float16 hj = (_Float16)vv;
            h[j] = hj;
            l[j] = (_Float16)((vv - (float)hj) * 2048.0f);
        }
        *reinterpret_cast<half4t*>(th + (size_t)(n0 + nn) * kD + k0 + c4) = h;
        *reinterpret_cast<half4t*>(tl + (size_t)(n0 + nn) * kD + k0 + c4) = l;
    }
}

// ---------------------------------------------------------------------------
// GEMM1 split-f16 3-pass MFMA, fused gelu + GEMM2 partial.
// grid = 512, block = 256 (4 waves).
//
// R3: XCD-pairing swizzle -- each XCD gets 2 hSplits x 32 contiguous
// rowBlocks, so the 32 same-hSplit blocks per XCD stream the SAME B-chunk
// data near-synchronously (L2-resident, 32x reuse) and A-slabs get 2x
// same-XCD reuse.  stageB moved one phase earlier (full-step latency
// headroom for B(t+1)).  K-loop otherwise as R2: 2-sub-phase, counted
// vmcnt(4), setprio around MFMA clusters, de-serialized epilogue.
// ---------------------------------------------------------------------------
__global__ __launch_bounds__(256, 2)
void gemm1_mfma(const _Float16* __restrict__ xh, const float* __restrict__ b1,
                const float* __restrict__ W2, float* __restrict__ dst,
                int atomicMode)
{
    __shared__ __align__(16) float smem[2 * BUF_FLOATS];   // 67584 B: 2 staging bufs / gS

    const int t = threadIdx.x;
    const int lane = t & 63;
    const int w = t >> 6;
    const int bx = blockIdx.x;
    // XCD-pairing map: xcd = bx&7 (dispatch round-robin heuristic)
    const int xcd = bx & 7;
    const int j8 = bx >> 3;                     // 0..63
    const int hSplit = 2 * (xcd & 1) + (j8 & 1);
    const int rowBlock = (xcd >> 1) * 32 + (j8 >> 1);
    const int rowBase = rowBlock * 128;

    const int mw = (w >> 1) * 64;
    const int nc32 = (w & 1) * 32;      // column sub-offset within each 64-col half

    // --- staging source offsets (f16 elements rel. to xh), source-permuted
    unsigned int gofsA[4], gofsB[4];
    #pragma unroll
    for (int i = 0; i < 8; ++i) {
        const int c = i * 256 + t;          // slot 0..2047 (16 B each)
        const int tile = c >> 9;            // 0:Ah 1:Al 2:Bh 3:Bl
        const int s = c & 511;
        const int row = s >> 2;
        const int pq = s & 3;
        const int q = pq ^ (row & 3) ^ ((row >> 2) & 3);
        const unsigned int plane =
            (tile == 0) ? (unsigned int)XH_OFF :
            (tile == 1) ? (unsigned int)XL_OFF :
            (tile == 2) ? (unsigned int)W1TH_OFF : (unsigned int)W1TL_OFF;
        if (tile < 2)
            gofsA[i] = plane + (unsigned int)(rowBase + row) * kD + q * 8;
        else
            gofsB[i - 4] = plane + (unsigned int)row * kD + q * 8;
    }

    // --- frag LDS offsets (f16 elements), swizzle-aware, kt-invariant
    int aOff[2][2], bOff[2][2];
    #pragma unroll
    for (int mt = 0; mt < 2; ++mt)
        #pragma unroll
        for (int ks = 0; ks < 2; ++ks) {
            const int row = mw + mt * 32 + (lane & 31);
            const int q = (lane >> 5) + 2 * ks;
            aOff[mt][ks] = row * 32 + ((q ^ (row & 3) ^ ((row >> 2) & 3)) * 8);
        }
    #pragma unroll
    for (int nt = 0; nt < 2; ++nt)
        #pragma unroll
        for (int ks = 0; ks < 2; ++ks) {
            const int row = nt * 64 + nc32 + (lane & 31);   // interleaved nt->col map
            const int q = (lane >> 5) + 2 * ks;
            bOff[nt][ks] = row * 32 + ((q ^ (row & 3) ^ ((row >> 2) & 3)) * 8);
        }

    // --- GEMM2 partial accumulators (4 rows x 8 experts per thread)
    const int g_r0 = (t >> 3) * 4;
    const int g_e0 = (t & 7) * 8;
    float lacc[4][8];
    #pragma unroll
    for (int i = 0; i < 4; ++i)
        #pragma unroll
        for (int j = 0; j < 8; ++j) lacc[i][j] = 0.0f;

    // --- staging halves: A planes (4 loads) / B planes (4 loads)
    auto stageA = [&](int buf, int nk) {
        _Float16* l = (_Float16*)smem + (size_t)buf * BUF_F16;
        #pragma unroll
        for (int i = 0; i < 4; ++i)
            async16(xh + gofsA[i] + nk, l + ((i * 256 + t) * 8));
    };
    auto stageB = [&](int buf, int nc, int nk) {
        _Float16* l = (_Float16*)smem + (size_t)buf * BUF_F16;
        const unsigned int hOff =
            (unsigned int)(hSplit * (CHUNKS * 128) + nc * 128) * kD;
        #pragma unroll
        for (int i = 0; i < 4; ++i)
            async16(xh + gofsB[i] + hOff + nk, l + (((i + 4) * 256 + t) * 8));
    };

    int cur = 0;
    stageA(0, 0);                       // prologue prefetch (chunk 0, kt 0)
    stageB(0, 0, 0);

    for (int chunk = 0; chunk < CHUNKS; ++chunk) {
        const int hBase = hSplit * (CHUNKS * 128) + chunk * 128;

        f32x16 accH[2][2], accL[2][2];
        #pragma unroll
        for (int a = 0; a < 2; ++a)
            #pragma unroll
            for (int b = 0; b < 2; ++b)
                #pragma unroll
                for (int r = 0; r < 16; ++r) { accH[a][b][r] = 0.0f; accL[a][b][r] = 0.0f; }

        for (int kt = 0; kt < kD; kt += 32) {
            const bool isLast = (chunk == CHUNKS - 1) && (kt == kD - 32);
            int nc = chunk, nk = kt + 32;
            if (nk == kD) { nc = chunk + 1; nk = 0; }

            const _Float16* lds = (const _Float16*)smem + (size_t)cur * BUF_F16;
            const int nbuf = cur ^ 1;

            if (!isLast) {
                stageA(nbuf, nk);                       // issue next-step A loads
                asm volatile("s_waitcnt vmcnt(4)" ::: "memory");  // prev step's 8 done
            } else {
                asm volatile("s_waitcnt vmcnt(0)" ::: "memory");
            }
            __builtin_amdgcn_s_barrier();               // B1: buf[cur] ready for all
            asm volatile("" ::: "memory");

            // ---- P0: ks = 0 --------------------------------------------------
            {
                half8 aH[2], aL[2], bH[2], bL[2];
                #pragma unroll
                for (int mt = 0; mt < 2; ++mt) {
                    aH[mt] = *reinterpret_cast<const half8*>(lds + aOff[mt][0]);
                    aL[mt] = *reinterpret_cast<const half8*>(lds + 4096 + aOff[mt][0]);
                }
                #pragma unroll
                for (int nt = 0; nt < 2; ++nt) {
                    bH[nt] = *reinterpret_cast<const half8*>(lds + 8192 + bOff[nt][0]);
                    bL[nt] = *reinterpret_cast<const half8*>(lds + 12288 + bOff[nt][0]);
                }
                if (!isLast) stageB(nbuf, nc, nk);      // issue next-step B loads early
                __builtin_amdgcn_s_setprio(1);
                #pragma unroll
                for (int mt = 0; mt < 2; ++mt)
                    #pragma unroll
                    for (int nt = 0; nt < 2; ++nt) {
                        accH[mt][nt] = __builtin_amdgcn_mfma_f32_32x32x16_f16(
                            aH[mt], bH[nt], accH[mt][nt], 0, 0, 0);
                        accL[mt][nt] = __builtin_amdgcn_mfma_f32_32x32x16_f16(
                            aH[mt], bL[nt], accL[mt][nt], 0, 0, 0);
                        accL[mt][nt] = __builtin_amdgcn_mfma_f32_32x32x16_f16(
                            aL[mt], bH[nt], accL[mt][nt], 0, 0, 0);
                    }
                __builtin_amdgcn_s_setprio(0);
                __builtin_amdgcn_sched_barrier(0);      // keep cluster in its phase
            }
            asm volatile("" ::: "memory");
            __builtin_amdgcn_s_barrier();               // B2: phase split
            asm volatile("" ::: "memory");

            // ---- P1: ks = 1 --------------------------------------------------
            {
                half8 aH[2], aL[2], bH[2], bL[2];
                #pragma unroll
                for (int mt = 0; mt < 2; ++mt) {
                    aH[mt] = *reinterpret_cast<const half8*>(lds + aOff[mt][1]);
                    aL[mt] = *reinterpret_cast<const half8*>(lds + 4096 + aOff[mt][1]);
                }
                #pragma unroll
                for (int nt = 0; nt < 2; ++nt) {
                    bH[nt] = *reinterpret_cast<const half8*>(lds + 8192 + bOff[nt][1]);
                    bL[nt] = *reinterpret_cast<const half8*>(lds + 12288 + bOff[nt][1]);
                }
                __builtin_amdgcn_s_setprio(1);
                #pragma unroll
                for (int mt = 0; mt < 2; ++mt)
                    #pragma unroll
                    for (int nt = 0; nt < 2; ++nt) {
                        accH[mt][nt] = __builtin_amdgcn_mfma_f32_32x32x16_f16(
                            aH[mt], bH[nt], accH[mt][nt], 0, 0, 0);
                        accL[mt][nt] = __builtin_amdgcn_mfma_f32_32x32x16_f16(
                            aH[mt], bL[nt], accL[mt][nt], 0, 0, 0);
                        accL[mt][nt] = __builtin_amdgcn_mfma_f32_32x32x16_f16(
                            aL[mt], bH[nt], accL[mt][nt], 0, 0, 0);
                    }
                __builtin_amdgcn_s_setprio(0);
                __builtin_amdgcn_sched_barrier(0);
            }
            asm volatile("s_waitcnt lgkmcnt(0)" ::: "memory");
            __builtin_amdgcn_s_barrier();               // B3: close step
            asm volatile("" ::: "memory");
            cur ^= 1;
        }

        // --- epilogue: combine + bias + gelu -> gS (g^T), GEMM2 partial.
        // gS aliases the just-read buffer; in-flight prefetch is in buf[cur].
        // All 4 waves participate in BOTH hf passes (interleaved nt->col map).
        float* gS = smem + (size_t)(cur ^ 1) * BUF_FLOATS;
        const float inv2048 = 1.0f / 2048.0f;
        const int hl = nc32 + (lane & 31);
        for (int hf = 0; hf < 2; ++hf) {
            if (hf) {   // GEMM2(hf=0) reads of gS must land before overwrite
                asm volatile("s_waitcnt lgkmcnt(0)" ::: "memory");
                __builtin_amdgcn_s_barrier();
                asm volatile("" ::: "memory");
            }
            const float bb = b1[hBase + hf * 64 + hl];
            #pragma unroll
            for (int mt = 0; mt < 2; ++mt) {
                #pragma unroll
                for (int rq = 0; rq < 4; ++rq) {
                    float vr[4];
                    #pragma unroll
                    for (int rr = 0; rr < 4; ++rr) {
                        const int r = rq * 4 + rr;
                        const float hv = accH[mt][hf][r] + accL[mt][hf][r] * inv2048 + bb;
                        vr[rr] = 0.5f * hv * (1.0f + erff(hv * 0.70710678118654752f));
                    }
                    const int mrow = mw + mt * 32 + 8 * rq + 4 * (lane >> 5);
                    *reinterpret_cast<float4*>(gS + hl * GS_STRIDE + mrow) =
                        make_float4(vr[0], vr[1], vr[2], vr[3]);
                }
            }
            asm volatile("s_waitcnt lgkmcnt(0)" ::: "memory");
            __builtin_amdgcn_s_barrier();
            asm volatile("" ::: "memory");
            const float* W2p = W2 + (size_t)(hBase + hf * 64) * kE + g_e0;
            #pragma unroll 4
            for (int h = 0; h < 64; ++h) {
                const float4 gv = *reinterpret_cast<const float4*>(gS + h * GS_STRIDE + g_r0);
                const float4 w0 = *reinterpret_cast<const float4*>(W2p + (size_t)h * kE);
                const float4 w1 = *reinterpret_cast<const float4*>(W2p + (size_t)h * kE + 4);
                const float ga[4] = {gv.x, gv.y, gv.z, gv.w};
                const float wb[8] = {w0.x, w0.y, w0.z, w0.w, w1.x, w1.y, w1.z, w1.w};
                #pragma unroll
                for (int i = 0; i < 4; ++i)
                    #pragma unroll
                    for (int j = 0; j < 8; ++j)
                        lacc[i][j] = fmaf(ga[i], wb[j], lacc[i][j]);
            }
        }
        // gS reads must land before next chunk's stage overwrites this buffer
        asm volatile("s_waitcnt lgkmcnt(0)" ::: "memory");
        __builtin_amdgcn_s_barrier();
        asm volatile("" ::: "memory");
    }

    // --- write GEMM2 partial: exclusive slice (mode 0) or atomics (mode 1)
    if (atomicMode) {
        #pragma unroll
        for (int i = 0; i < 4; ++i)
            #pragma unroll
            for (int j = 0; j < 8; ++j)
                atomicAdd(dst + (size_t)(rowBase + g_r0 + i) * kE + g_e0 + j, lacc[i][j]);
    } else {
        float* drow = dst + ((size_t)hSplit * kN + rowBase + g_r0) * kE + g_e0;
        #pragma unroll
        for (int i = 0; i < 4; ++i) {
            *reinterpret_cast<float4*>(drow + (size_t)i * kE) =
                make_float4(lacc[i][0], lacc[i][1], lacc[i][2], lacc[i][3]);
            *reinterpret_cast<float4*>(drow + (size_t)i * kE + 4) =
                make_float4(lacc[i][4], lacc[i][5], lacc[i][6], lacc[i][7]);
        }
    }
}

// ---------------------------------------------------------------------------
// Fallback fp32 GEMM1 (verified R1 kernel) — used when ws is too small
// ---------------------------------------------------------------------------
__global__ __launch_bounds__(256, 2)
void gemm1_kernel(const float* __restrict__ x, const float* __restrict__ W1,
                  const float* __restrict__ b1, const float* __restrict__ W2,
                  float* __restrict__ logits)
{
    __shared__ __align__(16) float smem[64 * GS_STRIDE];
    float* As = smem;
    float* Bs = smem + 32 * 128;
    float* gS = smem;

    const int t  = threadIdx.x;
    const int bx = blockIdx.x;
    const int rowBlock = bx >> 2;
    const int hSplit   = bx & 3;
    const int rowBase  = rowBlock * 128;
    const int hBase0   = hSplit * 1024;

    const int ty = t >> 4;
    const int tx = t & 15;
    const int r0 = ty * 8;
    const int c0 = tx * 8;
    const int g_r0 = (t >> 3) * 4;
    const int g_e0 = (t & 7) * 8;

    float lacc[4][8];
    #pragma unroll
    for (int i = 0; i < 4; ++i)
        #pragma unroll
        for (int j = 0; j < 8; ++j) lacc[i][j] = 0.0f;

    for (int chunk = 0; chunk < 8; ++chunk) {
        const int hBase = hBase0 + chunk * 128;
        float C[8][8];
        #pragma unroll
        for (int i = 0; i < 8; ++i)
            #pragma unroll
            for (int j = 0; j < 8; ++j) C[i][j] = 0.0f;

        for (int kt = 0; kt < kD; kt += 32) {
            __syncthreads();
            #pragma unroll
            for (int i = 0; i < 4; ++i) {
                const int f  = t + 256 * i;
                const int m  = f >> 3;
                const int kq = (f & 7) * 4;
                const float4 v = *reinterpret_cast<const float4*>(
                    x + (size_t)(rowBase + m) * kD + kt + kq);
                As[(kq + 0) * 128 + m] = v.x;
                As[(kq + 1) * 128 + m] = v.y;
                As[(kq + 2) * 128 + m] = v.z;
                As[(kq + 3) * 128 + m] = v.w;
            }
            #pragma unroll
            for (int i = 0; i < 4; ++i) {
                const int f  = t + 256 * i;
                const int k  = f >> 5;
                const int n4 = (f & 31) * 4;
                *reinterpret_cast<float4*>(Bs + k * 128 + n4) =
                    *reinterpret_cast<const float4*>(W1 + (size_t)(kt + k) * kH + hBase + n4);
            }
            __syncthreads();
            #pragma unroll 8
            for (int k = 0; k < 32; ++k) {
                const float4 a0 = *reinterpret_cast<const float4*>(As + k * 128 + r0);
                const float4 a1 = *reinterpret_cast<const float4*>(As + k * 128 + r0 + 4);
                const float4 b0 = *reinterpret_cast<const float4*>(Bs + k * 128 + c0);
                const float4 b1v = *reinterpret_cast<const float4*>(Bs + k * 128 + c0 + 4);
                const float a[8] = {a0.x, a0.y, a0.z, a0.w, a1.x, a1.y, a1.z, a1.w};
                const float b[8] = {b0.x, b0.y, b0.z, b0.w, b1v.x, b1v.y, b1v.z, b1v.w};
                #pragma unroll
                for (int i = 0; i < 8; ++i)
                    #pragma unroll
                    for (int j = 0; j < 8; ++j)
                        C[i][j] = fmaf(a[i], b[j], C[i][j]);
            }
        }

        #pragma unroll
        for (int j = 0; j < 8; ++j) {
            const float bb = b1[hBase + c0 + j];
            #pragma unroll
            for (int i = 0; i < 8; ++i) {
                const float hv = C[i][j] + bb;
                C[i][j] = 0.5f * hv * (1.0f + erff(hv * 0.70710678118654752f));
            }
        }

        for (int half = 0; half < 2; ++half) {
            __syncthreads();
            if ((tx >> 3) == half) {
                const int hloc0 = c0 - half * 64;
                #pragma unroll
                for (int j = 0; j < 8; ++j) {
                    const float4 col = make_float4(C[0][j], C[1][j], C[2][j], C[3][j]);
                    const float4 col2 = make_float4(C[4][j], C[5][j], C[6][j], C[7][j]);
                    *reinterpret_cast<float4*>(gS + (hloc0 + j) * GS_STRIDE + r0)     = col;
                    *reinterpret_cast<float4*>(gS + (hloc0 + j) * GS_STRIDE + r0 + 4) = col2;
                }
            }
            __syncthreads();
            const float* W2p = W2 + (size_t)(hBase + half * 64) * kE + g_e0;
            #pragma unroll 4
            for (int h = 0; h < 64; ++h) {
                const float4 gv = *reinterpret_cast<const float4*>(gS + h * GS_STRIDE + g_r0);
                const float4 w0 = *reinterpret_cast<const float4*>(W2p + (size_t)h * kE);
                const float4 w1 = *reinterpret_cast<const float4*>(W2p + (size_t)h * kE + 4);
                const float ga[4] = {gv.x, gv.y, gv.z, gv.w};
                const float wb[8] = {w0.x, w0.y, w0.z, w0.w, w1.x, w1.y, w1.z, w1.w};
                #pragma unroll
                for (int i = 0; i < 4; ++i)
                    #pragma unroll
                    for (int j = 0; j < 8; ++j)
                        lacc[i][j] = fmaf(ga[i], wb[j], lacc[i][j]);
            }
        }
    }

    #pragma unroll
    for (int i = 0; i < 4; ++i)
        #pragma unroll
        for (int j = 0; j < 8; ++j)
            atomicAdd(logits + (size_t)(rowBase + g_r0 + i) * kE + g_e0 + j, lacc[i][j]);
}

// ---------------------------------------------------------------------------
// Router: logits from partials (mode 0) or logits buffer (mode 1); softmax,
// shared split, top-2 with min-index tie-break, indices written as float.
// ---------------------------------------------------------------------------
__global__ __launch_bounds__(256)
void router_kernel(const float* __restrict__ b2, const float* __restrict__ src,
                   int atomicMode, float* __restrict__ out)
{
    const int lane = threadIdx.x & 63;
    const int row  = blockIdx.x * 4 + (threadIdx.x >> 6);

    float logit;
    if (atomicMode) {
        logit = src[(size_t)row * kE + lane] + b2[lane];
    } else {
        const float* p = src + (size_t)row * kE + lane;
        logit = p[0] + p[(size_t)kN * kE] + p[(size_t)2 * kN * kE] +
                p[(size_t)3 * kN * kE] + b2[lane];
    }

    float m = logit;
    #pragma unroll
    for (int off = 32; off > 0; off >>= 1) m = fmaxf(m, __shfl_xor(m, off));
    const float p = expf(logit - m);
    float s = p;
    #pragma unroll
    for (int off = 32; off > 0; off >>= 1) s += __shfl_xor(s, off);
    const float w = p / s;

    out[OFF_W + (size_t)row * kE + lane] = w;
    if (lane < kShared) out[OFF_GW + (size_t)row * kShared + lane] = w;

    float v1 = (lane >= kShared) ? w : -1.0f;
    int   i1 = lane - kShared;
    #pragma unroll
    for (int off = 32; off > 0; off >>= 1) {
        const float ov = __shfl_xor(v1, off);
        const int   oi = __shfl_xor(i1, off);
        if (ov > v1 || (ov == v1 && oi < i1)) { v1 = ov; i1 = oi; }
    }
    float v2 = (lane >= kShared && (lane - kShared) != i1) ? w : -1.0f;
    int   i2 = lane - kShared;
    #pragma unroll
    for (int off = 32; off > 0; off >>= 1) {
        const float ov = __shfl_xor(v2, off);
        const int   oi = __shfl_xor(i2, off);
        if (ov > v2 || (ov == v2 && oi < i2)) { v2 = ov; i2 = oi; }
    }
    if (lane == 0) {
        out[OFF_LW + (size_t)row * 2 + 0] = v1;
        out[OFF_LW + (size_t)row * 2 + 1] = v2;
        out[OFF_LI + (size_t)row * 2 + 0] = (float)i1;
        out[OFF_LI + (size_t)row * 2 + 1] = (float)i2;
    }
}

extern "C" void kernel_launch(void* const* d_in, const int* in_sizes, int n_in,
                              void* d_out, int out_size, void* d_ws, size_t ws_size,
                              hipStream_t stream)
{
    const float* x  = (const float*)d_in[0];
    const float* W1 = (const float*)d_in[1];
    const float* b1 = (const float*)d_in[2];
    const float* W2 = (const float*)d_in[3];
    const float* b2 = (const float*)d_in[4];
    float* out = (float*)d_out;
    float* logits = out + OFF_W;

    if (ws_size >= WS_BASE) {
        _Float16* base = (_Float16*)d_ws;
        const int atomicMode = (ws_size >= WS_FULL) ? 0 : 1;
        float* dst = atomicMode ? logits : ((float*)d_ws + PART_FLOAT_OFF);
        if (atomicMode)
            hipMemsetAsync(logits, 0, (size_t)kN * kE * sizeof(float), stream);
        hipLaunchKernelGGL(convert_xw, dim3(CXB + (kD / 64) * (kH / 64)), dim3(256), 0, stream,
                           x, base + XH_OFF, base + XL_OFF,
                           W1, base + W1TH_OFF, base + W1TL_OFF);
        hipLaunchKernelGGL(gemm1_mfma, dim3((kN / 128) * HSPLIT), dim3(256), 0, stream,
                           base + XH_OFF, b1, W2, dst, atomicMode);
        hipLaunchKernelGGL(router_kernel, dim3(kN / 4), dim3(256), 0, stream,
                           b2, dst, atomicMode, out);
    } else {
        hipMemsetAsync(logits, 0, (size_t)kN * kE * sizeof(float), stream);
        hipLaunchKernelGGL(gemm1_kernel, dim3((kN / 128) * 4), dim3(256), 0, stream,
                           x, W1, b1, W2, logits);
        hipLaunchKernelGGL(router_kernel, dim3(kN / 4), dim3(256), 0, stream,
                           b2, logits, 1, out);
    }
}